// Round 2
// baseline (159.841 us; speedup 1.0000x reference)
//
#include <hip/hip_runtime.h>

#define EPS_F 1e-6f
#define BLK   256

typedef float v2f __attribute__((ext_vector_type(2)));
typedef float v4f __attribute__((ext_vector_type(4)));

// ---- Kernel 1: w = sigmoid(w_raw), 19x19 = 361 floats into d_ws ----
__global__ void sigmoid_w_kernel(const float* __restrict__ w_raw,
                                 float* __restrict__ w) {
    int i = threadIdx.x;
    if (i < 361) {
        w[i] = 1.0f / (1.0f + expf(-w_raw[i]));
    }
}

__device__ __forceinline__ v2f vsplat(float s) {
    v2f r; r.x = s; r.y = s; return r;
}

// mix on two samples at once: w*min + (1-w)*max = w*(mn-mx) + mx
// min/max scalarize (no packed variant); sub and fma become v_pk_add/v_pk_fma.
__device__ __forceinline__ v2f vmix(v2f a, v2f b, float wv) {
    v2f mn, mx;
    mn.x = fminf(a.x, b.x); mn.y = fminf(a.y, b.y);
    mx.x = fmaxf(a.x, b.x); mx.y = fmaxf(a.y, b.y);
    return vsplat(wv) * (mn - mx) + mx;
}

__device__ __forceinline__ float clampf(float r) {
    return __builtin_amdgcn_fmed3f(r, EPS_F, 1.0f - EPS_F);  // 1 instr clamp
}

// ---- Kernel 2: 2 samples/thread packed in float2 lanes, LDS copy-out x2 ----
__global__ __launch_bounds__(BLK) void tree_forward_kernel(
    const float* __restrict__ c20,   // (B, 20)
    const float* __restrict__ w,     // (19, 19) sigmoid'd
    float* __restrict__ out,         // (B, 19)
    int B)
{
    __shared__ float so[BLK * 19];   // 19456 B -> LDS allows 8 blocks/CU

    const int tid = threadIdx.x;
    const int S0  = blockIdx.x * (2 * BLK);  // block covers 512 samples
    const int sA  = S0 + tid;                // phase-A sample (lane .x)
    const int sB  = S0 + BLK + tid;          // phase-B sample (lane .y)

    // Layer-0 min/max pairs are tree-independent; consume x[] immediately so
    // only d/mx (20 float2 = 80 VGPR) stay live, not the raw inputs.
    v2f d[10], mx[10];
    {
        const float4* pA = reinterpret_cast<const float4*>(c20 + (size_t)sA * 20);
        const float4* pB = reinterpret_cast<const float4*>(c20 + (size_t)sB * 20);
        const bool vA = (sA < B), vB = (sB < B);
        #pragma unroll
        for (int q = 0; q < 5; ++q) {
            float4 a4 = vA ? pA[q] : make_float4(0.f, 0.f, 0.f, 0.f);
            float4 b4 = vB ? pB[q] : make_float4(0.f, 0.f, 0.f, 0.f);
            {   // pair 2q: elements (0,1) of this float4
                v2f a, b;
                a.x = a4.x; a.y = b4.x;
                b.x = a4.y; b.y = b4.y;
                v2f mn;
                mn.x       = fminf(a.x, b.x); mn.y       = fminf(a.y, b.y);
                mx[2*q].x  = fmaxf(a.x, b.x); mx[2*q].y  = fmaxf(a.y, b.y);
                d[2*q] = mn - mx[2*q];                    // v_pk_add (neg)
            }
            {   // pair 2q+1: elements (2,3)
                v2f a, b;
                a.x = a4.z; a.y = b4.z;
                b.x = a4.w; b.y = b4.w;
                v2f mn;
                mn.x        = fminf(a.x, b.x); mn.y        = fminf(a.y, b.y);
                mx[2*q+1].x = fmaxf(a.x, b.x); mx[2*q+1].y = fmaxf(a.y, b.y);
                d[2*q+1] = mn - mx[2*q+1];
            }
        }
    }

    float oB[19];                       // phase-B results held in regs
    float* __restrict__ o = &so[tid * 19];

    #pragma unroll
    for (int t = 0; t < 19; ++t) {
        const float* wr = w + t * 19;   // uniform -> s_loads
        v2f z[5];
        #pragma unroll
        for (int k = 0; k < 5; ++k) {
            // layer 0: y = w*d + mx  -> one v_pk_fma per pair of samples
            v2f ya = vsplat(wr[2*k    ]) * d[2*k    ] + mx[2*k    ];
            v2f yb = vsplat(wr[2*k + 1]) * d[2*k + 1] + mx[2*k + 1];
            z[k] = vmix(ya, yb, wr[10 + k]);
        }
        v2f u0 = vmix(z[0], z[1], wr[15]);
        v2f u1 = vmix(z[2], z[3], wr[16]);
        v2f v  = vmix(u0, u1, wr[17]);
        v2f r  = vmix(v, z[4], wr[18]);
        o[t]  = clampf(r.x);
        oB[t] = clampf(r.y);
    }

    __syncthreads();

    const int nDw = B * 19;             // 19e6 fits comfortably in int32
    const v4f* ls = reinterpret_cast<const v4f*>(so);

    // phase A copy-out: BLK*19 = 4864 dwords = 1216 float4, coalesced, nt
    {
        const int baseDw = S0 * 19;     // divisible by 4
        #pragma unroll
        for (int i = tid; i < (BLK * 19) / 4; i += BLK) {
            int g = baseDw + i * 4;
            if (g + 3 < nDw) {
                __builtin_nontemporal_store(ls[i], reinterpret_cast<v4f*>(out + g));
            } else if (g < nDw) {
                v4f v4 = ls[i];
                out[g] = v4.x;
                if (g + 1 < nDw) out[g + 1] = v4.y;
                if (g + 2 < nDw) out[g + 2] = v4.z;
            }
        }
    }

    __syncthreads();

    #pragma unroll
    for (int t = 0; t < 19; ++t) o[t] = oB[t];

    __syncthreads();

    // phase B copy-out
    {
        const int baseDw = (S0 + BLK) * 19;
        #pragma unroll
        for (int i = tid; i < (BLK * 19) / 4; i += BLK) {
            int g = baseDw + i * 4;
            if (g + 3 < nDw) {
                __builtin_nontemporal_store(ls[i], reinterpret_cast<v4f*>(out + g));
            } else if (g < nDw) {
                v4f v4 = ls[i];
                out[g] = v4.x;
                if (g + 1 < nDw) out[g + 1] = v4.y;
                if (g + 2 < nDw) out[g + 2] = v4.z;
            }
        }
    }
}

extern "C" void kernel_launch(void* const* d_in, const int* in_sizes, int n_in,
                              void* d_out, int out_size, void* d_ws, size_t ws_size,
                              hipStream_t stream) {
    // setup_inputs order: p1 (B,) int, p2 (B,) int, c20 (B,20) f32, w_raw (19,19) f32
    const float* c20   = (const float*)d_in[2];
    const float* w_raw = (const float*)d_in[3];
    float* out = (float*)d_out;
    float* w   = (float*)d_ws;   // 361 floats of scratch

    int B = in_sizes[0];

    sigmoid_w_kernel<<<1, 384, 0, stream>>>(w_raw, w);

    int grid = (B + 2 * BLK - 1) / (2 * BLK);
    tree_forward_kernel<<<grid, BLK, 0, stream>>>(c20, w, out, B);
}

// Round 6
// 153.820 us; speedup vs baseline: 1.0391x; 1.0391x over previous
//
#include <hip/hip_runtime.h>

#define EPS_F 1e-6f
#define BLK   256

typedef float v2f __attribute__((ext_vector_type(2)));
typedef float v4f __attribute__((ext_vector_type(4)));

// ---- Kernel 1: wt[node][20] = sigmoid(w_raw[tree][node]), transposed+padded.
// Pad stride 20 so a tree-PAIR's weights (even tree first) are 8B-aligned ->
// one s_load_dwordx2 feeds v_pk_fma as a 64-bit scalar operand.
__global__ void sigmoid_w_kernel(const float* __restrict__ w_raw,
                                 float* __restrict__ wt) {
    int i = threadIdx.x;
    if (i < 361) {
        int t = i / 19;      // tree
        int k = i % 19;      // node
        wt[k * 20 + t] = 1.0f / (1.0f + expf(-w_raw[i]));
    }
}

__device__ __forceinline__ v2f vsplat(float s) {
    v2f r; r.x = s; r.y = s; return r;
}

// mix for TWO TREES at once (same sample): w*mn + (1-w)*mx = w*(mn-mx) + mx
// min/max scalarize (2+2 ops); sub and fma pack (v_pk_add + v_pk_fma).
__device__ __forceinline__ v2f pairmix(v2f a, v2f b, v2f wv) {
    v2f mn, mx;
    mn.x = fminf(a.x, b.x); mn.y = fminf(a.y, b.y);
    mx.x = fmaxf(a.x, b.x); mx.y = fmaxf(a.y, b.y);
    return wv * (mn - mx) + mx;
}

__device__ __forceinline__ float clampf(float r) {
    return __builtin_amdgcn_fmed3f(r, EPS_F, 1.0f - EPS_F);  // 1 instr clamp
}

// ---- Kernel 2: 1 sample/thread, trees packed in v2f PAIRS, LDS copy-out ----
__global__ __launch_bounds__(BLK) void tree_forward_kernel(
    const float* __restrict__ c20,   // (B, 20)
    const float* __restrict__ wt,    // (19, 20) sigmoid'd, transposed+padded
    float* __restrict__ out,         // (B, 19)
    int B)
{
    __shared__ float so[BLK * 19];   // 19456 B -> 8 blocks/CU cap

    const int tid = threadIdx.x;
    const int S0  = blockIdx.x * BLK;
    const int s   = S0 + tid;

    // Layer-0 min/max pairs are tree-independent: compute once.
    float mx[10], d[10];
    {
        const float4* p = reinterpret_cast<const float4*>(c20 + (size_t)s * 20);
        const bool valid = (s < B);
        #pragma unroll
        for (int q = 0; q < 5; ++q) {
            float4 v = valid ? p[q] : make_float4(0.f, 0.f, 0.f, 0.f);
            {
                float mn = fminf(v.x, v.y);
                mx[2*q] = fmaxf(v.x, v.y);
                d[2*q]  = mn - mx[2*q];
            }
            {
                float mn = fminf(v.z, v.w);
                mx[2*q+1] = fmaxf(v.z, v.w);
                d[2*q+1]  = mn - mx[2*q+1];
            }
        }
    }

    float* __restrict__ o = &so[tid * 19];

    // 9 tree pairs; lanes of each v2f hold (tree 2tp, tree 2tp+1).
    #pragma unroll
    for (int tp = 0; tp < 9; ++tp) {
        const float* wp = wt + 2 * tp;   // uniform; node k pair at wp[20k..20k+1]

        v2f y[10];
        #pragma unroll
        for (int k = 0; k < 10; ++k) {
            v2f wk = *reinterpret_cast<const v2f*>(wp + 20 * k); // s_load_dwordx2
            y[k] = wk * vsplat(d[k]) + vsplat(mx[k]);            // 1 v_pk_fma
        }

        v2f z[5];
        #pragma unroll
        for (int k = 0; k < 5; ++k) {
            v2f wk = *reinterpret_cast<const v2f*>(wp + 20 * (10 + k));
            z[k] = pairmix(y[2*k], y[2*k+1], wk);
        }

        v2f u0 = pairmix(z[0], z[1], *reinterpret_cast<const v2f*>(wp + 20 * 15));
        v2f u1 = pairmix(z[2], z[3], *reinterpret_cast<const v2f*>(wp + 20 * 16));
        v2f v  = pairmix(u0, u1,   *reinterpret_cast<const v2f*>(wp + 20 * 17));
        v2f r  = pairmix(v, z[4],  *reinterpret_cast<const v2f*>(wp + 20 * 18));

        o[2*tp]     = clampf(r.x);
        o[2*tp + 1] = clampf(r.y);
    }

    // tree 18 (last, unpaired) — scalar path
    {
        const float* wr = wt + 18;   // node k at wr[20k]
        float y[10];
        #pragma unroll
        for (int k = 0; k < 10; ++k)
            y[k] = fmaf(wr[20 * k], d[k], mx[k]);
        float z[5];
        #pragma unroll
        for (int k = 0; k < 5; ++k) {
            float mn = fminf(y[2*k], y[2*k+1]);
            float mxx = fmaxf(y[2*k], y[2*k+1]);
            z[k] = fmaf(wr[20 * (10 + k)], mn - mxx, mxx);
        }
        float mn, mxx;
        mn = fminf(z[0], z[1]); mxx = fmaxf(z[0], z[1]);
        float u0 = fmaf(wr[20 * 15], mn - mxx, mxx);
        mn = fminf(z[2], z[3]); mxx = fmaxf(z[2], z[3]);
        float u1 = fmaf(wr[20 * 16], mn - mxx, mxx);
        mn = fminf(u0, u1); mxx = fmaxf(u0, u1);
        float v0 = fmaf(wr[20 * 17], mn - mxx, mxx);
        mn = fminf(v0, z[4]); mxx = fmaxf(v0, z[4]);
        float rr = fmaf(wr[20 * 18], mn - mxx, mxx);
        o[18] = clampf(rr);
    }

    __syncthreads();

    // Cooperative coalesced copy-out: BLK*19 = 4864 dwords = 1216 float4, nt.
    const int nDw    = B * 19;          // 1.9e7 fits int32
    const int baseDw = S0 * 19;         // divisible by 4
    const v4f* ls = reinterpret_cast<const v4f*>(so);

    #pragma unroll
    for (int i = tid; i < (BLK * 19) / 4; i += BLK) {
        int g = baseDw + i * 4;
        if (g + 3 < nDw) {
            __builtin_nontemporal_store(ls[i], reinterpret_cast<v4f*>(out + g));
        } else if (g < nDw) {
            v4f v4 = ls[i];
            out[g] = v4.x;
            if (g + 1 < nDw) out[g + 1] = v4.y;
            if (g + 2 < nDw) out[g + 2] = v4.z;
        }
    }
}

extern "C" void kernel_launch(void* const* d_in, const int* in_sizes, int n_in,
                              void* d_out, int out_size, void* d_ws, size_t ws_size,
                              hipStream_t stream) {
    // setup_inputs order: p1 (B,) int, p2 (B,) int, c20 (B,20) f32, w_raw (19,19) f32
    const float* c20   = (const float*)d_in[2];
    const float* w_raw = (const float*)d_in[3];
    float* out = (float*)d_out;
    float* wt  = (float*)d_ws;   // 380 floats of scratch (19x20 transposed)

    int B = in_sizes[0];

    sigmoid_w_kernel<<<1, 384, 0, stream>>>(w_raw, wt);

    int grid = (B + BLK - 1) / BLK;
    tree_forward_kernel<<<grid, BLK, 0, stream>>>(c20, wt, out, B);
}